// Round 1
// baseline (412.417 us; speedup 1.0000x reference)
//
#include <hip/hip_runtime.h>

// Butterfly multiply, n=1024, log_n=10, nstacks=nblocks=1, increasing stride.
// x: (32768, 1024) f32; twiddle: (10, 512, 2, 2) f32; bias: (1024,) f32.
//
// Mapping: one wave (64 lanes) processes ROWS_PER_WAVE rows. Lane l holds
// elements [l*16, l*16+16) of each row in registers.
//   stages 0..3 (stride 1..8):  within-lane register butterflies
//   stages 4..9 (stride 16..512): __shfl_xor with mask 1<<(stage-4)
// Twiddle for stage s, position p: pair = p with bit s deleted,
// 2x2 at tw[s*2048 + pair*4]. For cross-lane stages a lane only needs its
// own output row of the 2x2; the o0/o1 swap is folded into the load.
//
// ROWS_PER_WAVE=2 (was 4): the v[][] state must stay live across ALL stages;
// at 4 rows that's 64 VGPRs of persistent state + 32 of twiddle coeffs +
// addressing, which overflowed the 64-VGPR allocation (unified VGPR/AGPR on
// gfx950 -> scratch spills -> latency-bound, VALUBusy 7%). At 2 rows the
// live set (~90-100) fits the launch_bounds(256,2) budget with no spills.

#define ROWS_PER_WAVE 2
#define N 1024

__global__ __launch_bounds__(256, 2) void butterfly_kernel(
    const float* __restrict__ x,
    const float* __restrict__ tw,
    const float* __restrict__ bias,
    float* __restrict__ out,
    int nRows)
{
    const int lane = threadIdx.x & 63;
    const int waveInBlock = threadIdx.x >> 6;
    const int waveId = blockIdx.x * 4 + waveInBlock;
    const long rowBase = (long)waveId * ROWS_PER_WAVE;
    if (rowBase >= nRows) return;

    const int off = lane * 16;

    float v[ROWS_PER_WAVE][16];

    // ---- load rows (coalesced: wave covers 1024 consecutive floats) ----
    #pragma unroll
    for (int r = 0; r < ROWS_PER_WAVE; ++r) {
        const float4* p = (const float4*)(x + (rowBase + r) * N + off);
        #pragma unroll
        for (int q = 0; q < 4; ++q) {
            float4 f = p[q];
            v[r][q*4+0] = f.x; v[r][q*4+1] = f.y;
            v[r][q*4+2] = f.z; v[r][q*4+3] = f.w;
        }
    }

    // ---- stages 0..3: within-lane (stride 1,2,4,8) ----
    #pragma unroll
    for (int stage = 0; stage < 4; ++stage) {
        const int s = 1 << stage;
        // lane's 8 pairs are twiddle indices [lane*8, lane*8+8) -> 32 consec floats
        float t[32];
        const float4* tp = (const float4*)(tw + stage * 2048 + lane * 32);
        #pragma unroll
        for (int q = 0; q < 8; ++q) {
            float4 f = tp[q];
            t[q*4+0] = f.x; t[q*4+1] = f.y; t[q*4+2] = f.z; t[q*4+3] = f.w;
        }
        #pragma unroll
        for (int r = 0; r < ROWS_PER_WAVE; ++r) {
            #pragma unroll
            for (int j = 0; j < 8; ++j) {
                const int p0 = ((j >> stage) << (stage + 1)) | (j & (s - 1));
                const int p1 = p0 | s;
                float a = v[r][p0], b = v[r][p1];
                v[r][p0] = t[j*4+0] * a + t[j*4+1] * b;
                v[r][p1] = t[j*4+2] * a + t[j*4+3] * b;
            }
        }
    }

    // ---- stages 4..9: cross-lane (stride 16..512) ----
    #pragma unroll
    for (int stage = 4; stage < 10; ++stage) {
        const int lm = stage - 4;
        const int m = 1 << lm;
        const int i = (lane >> lm) & 1;                        // my row of the 2x2
        const int pl = ((lane >> (lm + 1)) << lm) | (lane & (m - 1)); // lane w/ bit lm deleted
        // my 16 pairs are twiddle indices [pl*16, pl*16+16)
        const float* tb = tw + stage * 2048 + pl * 64 + i * 2;
        float ta_[16], tb_[16];   // coeff of (mine, other) — swap folded in here
        #pragma unroll
        for (int k = 0; k < 16; ++k) {
            float2 raw = *(const float2*)(tb + k * 4);   // (t[i][0], t[i][1])
            ta_[k] = i ? raw.y : raw.x;   // coeff of my element  (o_i)
            tb_[k] = i ? raw.x : raw.y;   // coeff of partner     (o_{1-i})
        }
        #pragma unroll
        for (int r = 0; r < ROWS_PER_WAVE; ++r) {
            #pragma unroll
            for (int k = 0; k < 16; ++k) {
                float mine  = v[r][k];
                float other = __shfl_xor(mine, m, 64);
                v[r][k] = ta_[k] * mine + tb_[k] * other;
            }
        }
    }

    // ---- bias + store ----
    float bv[16];
    {
        const float4* bp = (const float4*)(bias + off);
        #pragma unroll
        for (int q = 0; q < 4; ++q) {
            float4 f = bp[q];
            bv[q*4+0] = f.x; bv[q*4+1] = f.y;
            bv[q*4+2] = f.z; bv[q*4+3] = f.w;
        }
    }
    #pragma unroll
    for (int r = 0; r < ROWS_PER_WAVE; ++r) {
        float4* p = (float4*)(out + (rowBase + r) * N + off);
        #pragma unroll
        for (int q = 0; q < 4; ++q) {
            float4 f;
            f.x = v[r][q*4+0] + bv[q*4+0];
            f.y = v[r][q*4+1] + bv[q*4+1];
            f.z = v[r][q*4+2] + bv[q*4+2];
            f.w = v[r][q*4+3] + bv[q*4+3];
            p[q] = f;
        }
    }
}

extern "C" void kernel_launch(void* const* d_in, const int* in_sizes, int n_in,
                              void* d_out, int out_size, void* d_ws, size_t ws_size,
                              hipStream_t stream) {
    const float* x    = (const float*)d_in[0];
    const float* tw   = (const float*)d_in[1];
    const float* bias = (const float*)d_in[2];
    float* out = (float*)d_out;

    const int nRows = in_sizes[0] / N;                       // 32768
    const int waves = (nRows + ROWS_PER_WAVE - 1) / ROWS_PER_WAVE;
    const int blocks = (waves + 3) / 4;                      // 4 waves / block

    butterfly_kernel<<<blocks, 256, 0, stream>>>(x, tw, bias, out, nRows);
}

// Round 2
// 299.507 us; speedup vs baseline: 1.3770x; 1.3770x over previous
//
#include <hip/hip_runtime.h>

// Butterfly multiply, n=1024, log_n=10, nstacks=nblocks=1, increasing stride.
// x: (32768, 1024) f32; twiddle: (10, 512, 2, 2) f32; bias: (1024,) f32.
//
// Mapping: one wave (64 lanes) processes ROWS_PER_WAVE rows. Lane l holds
// elements [l*16, l*16+16) of each row in registers.
//   stages 0..3 (stride 1..8):  within-lane register butterflies
//   stages 4..9 (stride 16..512): __shfl_xor with mask 1<<(stage-4)
//
// Round-2 change: the twiddle table (80 KB) is re-permuted ONCE per launch
// into workspace `ws` in a LANE-MAJOR layout, so every twiddle load in the
// main kernel is a fully-coalesced wave-level float4 load (16 fully-used
// cachelines/instr instead of 64 partially-used). Rocprof showed the old
// strided loads made the kernel TA/L1-transaction-bound (VALUBusy 7.5%,
// HBM 18%, dur 4x roofline; regression when waves doubled at RPW=2).
// The i-dependent (mine/other) coefficient swap of cross-lane stages is
// folded into the permutation, removing all v_cndmask selects.
//
// ws layout, per stage s (2048 floats each, ws + s*2048):
//   s<4 : word  q*256 + l*4 + c    holds tw word l*32 + q*4 + c
//         -> lane l reads float4 ws4[s*512 + q*64 + l], q=0..7  (t[q*4+c])
//   s>=4: word  (k>>1)*256 + l*4 + (k&1)*2 + (j^i)  holds tw word
//         pl*64 + k*4 + i*2 + j,  where lane l = insert(i at bit lm of pl)
//         -> lane l reads float4 ws4[s*512 + kk*64 + l], kk=0..7 giving
//            (ta[2kk], tb[2kk], ta[2kk+1], tb[2kk+1])

#define ROWS_PER_WAVE 4
#define N 1024

__global__ __launch_bounds__(256) void permute_tw_kernel(
    const float* __restrict__ tw, float* __restrict__ ws)
{
    const int s = blockIdx.x;          // 10 blocks, one per stage
    const int t = threadIdx.x;         // 256 threads
    #pragma unroll
    for (int it = 0; it < 8; ++it) {
        const int g = it * 256 + t;    // word index within stage, coalesced read
        const float val = tw[s * 2048 + g];
        int dst;
        if (s < 4) {
            const int l  = g >> 5;
            const int r  = g & 31;
            dst = (r >> 2) * 256 + l * 4 + (r & 3);
        } else {
            const int p  = g >> 2;         // pair index 0..511
            const int c  = g & 3;          // 2x2 entry
            const int i  = c >> 1;
            const int j  = c & 1;
            const int pl = p >> 4;
            const int k  = p & 15;
            const int lm = s - 4;
            const int m  = 1 << lm;
            const int l  = ((pl >> lm) << (lm + 1)) | (i << lm) | (pl & (m - 1));
            dst = (k >> 1) * 256 + l * 4 + (k & 1) * 2 + (j ^ i);
        }
        ws[s * 2048 + dst] = val;
    }
}

__global__ __launch_bounds__(256, 4) void butterfly_kernel(
    const float* __restrict__ x,
    const float* __restrict__ ws,      // permuted twiddle (see header comment)
    const float* __restrict__ bias,
    float* __restrict__ out,
    int nRows)
{
    const int lane = threadIdx.x & 63;
    const int waveInBlock = threadIdx.x >> 6;
    const int waveId = blockIdx.x * 4 + waveInBlock;
    const long rowBase = (long)waveId * ROWS_PER_WAVE;
    if (rowBase >= nRows) return;

    const int off = lane * 16;

    float v[ROWS_PER_WAVE][16];

    // ---- load rows (coalesced: wave covers 1024 consecutive floats) ----
    #pragma unroll
    for (int r = 0; r < ROWS_PER_WAVE; ++r) {
        const float4* p = (const float4*)(x + (rowBase + r) * N + off);
        #pragma unroll
        for (int q = 0; q < 4; ++q) {
            float4 f = p[q];
            v[r][q*4+0] = f.x; v[r][q*4+1] = f.y;
            v[r][q*4+2] = f.z; v[r][q*4+3] = f.w;
        }
    }

    // ---- stages 0..3: within-lane (stride 1,2,4,8) ----
    #pragma unroll
    for (int stage = 0; stage < 4; ++stage) {
        const int s = 1 << stage;
        float t[32];
        const float4* tp = (const float4*)(ws + stage * 2048) + lane;
        #pragma unroll
        for (int q = 0; q < 8; ++q) {
            float4 f = tp[q * 64];         // coalesced: lanes read consecutive float4s
            t[q*4+0] = f.x; t[q*4+1] = f.y; t[q*4+2] = f.z; t[q*4+3] = f.w;
        }
        #pragma unroll
        for (int r = 0; r < ROWS_PER_WAVE; ++r) {
            #pragma unroll
            for (int j = 0; j < 8; ++j) {
                const int p0 = ((j >> stage) << (stage + 1)) | (j & (s - 1));
                const int p1 = p0 | s;
                float a = v[r][p0], b = v[r][p1];
                v[r][p0] = t[j*4+0] * a + t[j*4+1] * b;
                v[r][p1] = t[j*4+2] * a + t[j*4+3] * b;
            }
        }
    }

    // ---- stages 4..9: cross-lane (stride 16..512) ----
    #pragma unroll
    for (int stage = 4; stage < 10; ++stage) {
        const int m = 1 << (stage - 4);
        float ta_[16], tb_[16];            // coeff of (mine, partner), pre-swapped in ws
        const float4* tp = (const float4*)(ws + stage * 2048) + lane;
        #pragma unroll
        for (int kk = 0; kk < 8; ++kk) {
            float4 f = tp[kk * 64];        // coalesced
            ta_[2*kk+0] = f.x; tb_[2*kk+0] = f.y;
            ta_[2*kk+1] = f.z; tb_[2*kk+1] = f.w;
        }
        #pragma unroll
        for (int r = 0; r < ROWS_PER_WAVE; ++r) {
            #pragma unroll
            for (int k = 0; k < 16; ++k) {
                float mine  = v[r][k];
                float other = __shfl_xor(mine, m, 64);
                v[r][k] = ta_[k] * mine + tb_[k] * other;
            }
        }
    }

    // ---- bias + store ----
    float bv[16];
    {
        const float4* bp = (const float4*)(bias + off);
        #pragma unroll
        for (int q = 0; q < 4; ++q) {
            float4 f = bp[q];
            bv[q*4+0] = f.x; bv[q*4+1] = f.y;
            bv[q*4+2] = f.z; bv[q*4+3] = f.w;
        }
    }
    #pragma unroll
    for (int r = 0; r < ROWS_PER_WAVE; ++r) {
        float4* p = (float4*)(out + (rowBase + r) * N + off);
        #pragma unroll
        for (int q = 0; q < 4; ++q) {
            float4 f;
            f.x = v[r][q*4+0] + bv[q*4+0];
            f.y = v[r][q*4+1] + bv[q*4+1];
            f.z = v[r][q*4+2] + bv[q*4+2];
            f.w = v[r][q*4+3] + bv[q*4+3];
            p[q] = f;
        }
    }
}

extern "C" void kernel_launch(void* const* d_in, const int* in_sizes, int n_in,
                              void* d_out, int out_size, void* d_ws, size_t ws_size,
                              hipStream_t stream) {
    const float* x    = (const float*)d_in[0];
    const float* tw   = (const float*)d_in[1];
    const float* bias = (const float*)d_in[2];
    float* out = (float*)d_out;
    float* ws  = (float*)d_ws;                               // needs 80 KB

    // one-time (per launch) twiddle permutation into workspace
    permute_tw_kernel<<<10, 256, 0, stream>>>(tw, ws);

    const int nRows = in_sizes[0] / N;                       // 32768
    const int waves = (nRows + ROWS_PER_WAVE - 1) / ROWS_PER_WAVE;
    const int blocks = (waves + 3) / 4;                      // 4 waves / block

    butterfly_kernel<<<blocks, 256, 0, stream>>>(x, ws, bias, out, nRows);
}